// Round 4
// baseline (316.957 us; speedup 1.0000x reference)
//
#include <hip/hip_runtime.h>

// SinkhornOT — round 3: half-batch proj blocks (32KB LDS, 3-4 blocks/CU) with
// P spilled to ws as bf16; solver kernel absorbs qr+cdist. Fallback to the
// round-2 fused proj_cost path if ws_size is too small for P.
// B=2048, K=M=64, D=256, eps=0.05, 20 sinkhorn iters, 3 MESH iters.

typedef __attribute__((ext_vector_type(8))) short s16x8;
typedef __attribute__((ext_vector_type(4))) float f32x4;

#define OFF_T  2048
#define OFF_C  (2048 + 2048 * 4096)
#define OFF_TC (2048 + 2 * 2048 * 4096)

// ws layout (bytes): [0) W1t bf16 64K elems [131072) W2t [262144) norms f32
// 4096*64 [1310720) P bf16 4096*16384 [135528448) end
#define WS_NEED 135528448ull

__device__ __forceinline__ unsigned short f2bf(float x) {  // RNE f32->bf16
  unsigned u = __builtin_bit_cast(unsigned, x);
  u += 0x7fffu + ((u >> 16) & 1u);
  return (unsigned short)(u >> 16);
}
__device__ __forceinline__ float bf2f(unsigned short h) {
  return __builtin_bit_cast(float, ((unsigned)h) << 16);
}

#define MFMA16(a, b, c) __builtin_amdgcn_mfma_f32_16x16x32_bf16((a), (b), (c), 0, 0, 0)

__global__ void __launch_bounds__(256)
prep_w_kernel(const float* __restrict__ W1, const float* __restrict__ W2,
              short* __restrict__ W1t, short* __restrict__ W2t) {
  int i = blockIdx.x * 256 + threadIdx.x;   // 65536 threads exactly
  int d = i >> 8, e = i & 255;
  W1t[e * 256 + d] = (short)f2bf(W1[i]);
  W2t[e * 256 + d] = (short)f2bf(W2[i]);
}

// K-loop for the projection GEMMs. Wave computes RF row-frags x its 4
// col-frags. W fragments double-buffered in registers.
template <int RF>
__device__ __forceinline__ void gemm_kloop(const short* __restrict__ wb,
                                           const char* sm, int abase0, int asw,
                                           int koff0, f32x4 (&acc)[RF][4]) {
  s16x8 bwc[4], bwn[4];
#pragma unroll
  for (int nf = 0; nf < 4; ++nf) bwc[nf] = *(const s16x8*)(wb + nf * 4096);
#pragma unroll
  for (int ks = 0; ks < 8; ++ks) {
    if (ks < 7) {
#pragma unroll
      for (int nf = 0; nf < 4; ++nf)
        bwn[nf] = *(const s16x8*)(wb + nf * 4096 + (ks + 1) * 32);
    }
    const int ko = (ks * 64 + koff0) ^ asw;
    s16x8 af[RF];
#pragma unroll
    for (int rf = 0; rf < RF; ++rf)
      af[rf] = *(const s16x8*)(sm + rf * 8192 + abase0 + ko);
#pragma unroll
    for (int rf = 0; rf < RF; ++rf)
#pragma unroll
      for (int nf = 0; nf < 4; ++nf)
        acc[rf][nf] = MFMA16(af[rf], bwc[nf], acc[rf][nf]);
    if (ks < 7) {
#pragma unroll
      for (int nf = 0; nf < 4; ++nf) bwc[nf] = bwn[nf];
    }
  }
}

// ============ Kernel A (new): one (batch,side) per block, P -> ws ============
__global__ void __launch_bounds__(256, 3)
proj_kernel(const float* __restrict__ slots_q, const float* __restrict__ slots_r,
            const short* __restrict__ W1t, const short* __restrict__ W2t,
            const float* __restrict__ b1, const float* __restrict__ b2,
            short* __restrict__ Pws, float* __restrict__ norms_g) {
  __shared__ char smem[32768 + 1024];   // [64 rows][512B] bf16 tile + nbuf
  float* nbuf = (float*)(smem + 32768); // [4][64] norm partials

  const int bb   = blockIdx.x;          // (batch<<1)|side
  const int tid  = threadIdx.x;
  const int wv   = tid >> 6;
  const int lane = tid & 63;
  const int l15  = lane & 15;
  const int lhi  = lane >> 4;

  // ---------- stage X side (f32 -> bf16, swizzled) ----------
  {
    const float* src = ((bb & 1) ? slots_r : slots_q) + (size_t)(bb >> 1) * 16384;
#pragma unroll
    for (int i = 0; i < 16; ++i) {
      int idx4 = tid + 256 * i;               // float4 index
      int row = idx4 >> 6;                    // 0..63
      int colb = (idx4 & 63) * 8;
      float4 v = *(const float4*)(src + idx4 * 4);
      unsigned lo = (unsigned)f2bf(v.x) | ((unsigned)f2bf(v.y) << 16);
      unsigned hi = (unsigned)f2bf(v.z) | ((unsigned)f2bf(v.w) << 16);
      *(uint2*)(smem + row * 512 + (colb ^ ((row & 7) << 4))) = make_uint2(lo, hi);
    }
  }
  __syncthreads();

  const int abase0 = l15 * 512;
  const int asw    = (l15 & 7) << 4;
  const int koff0  = lhi * 16;
  const short* wb1 = W1t + (wv * 64 + l15) * 256 + lhi * 8;
  const short* wb2 = W2t + (wv * 64 + l15) * 256 + lhi * 8;

  float b1v[4], b2v[4];
#pragma unroll
  for (int nf = 0; nf < 4; ++nf) {
    b1v[nf] = b1[wv * 64 + nf * 16 + l15];
    b2v[nf] = b2[wv * 64 + nf * 16 + l15];
  }

  const f32x4 z4 = {0.f, 0.f, 0.f, 0.f};
  f32x4 acc[4][4];

  // ---------- GEMM1: H = relu(X*W1 + b1) ----------
#pragma unroll
  for (int rf = 0; rf < 4; ++rf)
#pragma unroll
    for (int nf = 0; nf < 4; ++nf) acc[rf][nf] = z4;
  gemm_kloop<4>(wb1, smem, abase0, asw, koff0, acc);
  __syncthreads();   // all waves done reading X
#pragma unroll
  for (int rf = 0; rf < 4; ++rf)
#pragma unroll
    for (int nf = 0; nf < 4; ++nf)
#pragma unroll
      for (int j = 0; j < 4; ++j) {
        int row = rf * 16 + lhi * 4 + j;
        int colb = (wv * 64 + nf * 16 + l15) * 2;
        *(unsigned short*)(smem + row * 512 + (colb ^ ((row & 7) << 4))) =
            f2bf(fmaxf(acc[rf][nf][j] + b1v[nf], 0.0f));
      }
  __syncthreads();

  // ---------- GEMM2: P = H*W2 + b2 ----------
#pragma unroll
  for (int rf = 0; rf < 4; ++rf)
#pragma unroll
    for (int nf = 0; nf < 4; ++nf) acc[rf][nf] = z4;
  gemm_kloop<4>(wb2, smem, abase0, asw, koff0, acc);
  __syncthreads();   // all waves done reading H -> tile free for P

  // write P (bf16) into tile + norm partials
  float p2[4][4];
#pragma unroll
  for (int rf = 0; rf < 4; ++rf)
#pragma unroll
    for (int j = 0; j < 4; ++j) {
      float s = 0.0f;
#pragma unroll
      for (int nf = 0; nf < 4; ++nf) {
        unsigned short h = f2bf(acc[rf][nf][j] + b2v[nf]);
        int row = rf * 16 + lhi * 4 + j;
        int colb = (wv * 64 + nf * 16 + l15) * 2;
        *(unsigned short*)(smem + row * 512 + (colb ^ ((row & 7) << 4))) = h;
        float f = bf2f(h);
        s += f * f;
      }
      p2[rf][j] = s;
    }
#pragma unroll
  for (int d = 1; d < 16; d <<= 1)
#pragma unroll
    for (int rf = 0; rf < 4; ++rf)
#pragma unroll
      for (int j = 0; j < 4; ++j) p2[rf][j] += __shfl_xor(p2[rf][j], d);
  if (l15 == 0) {
#pragma unroll
    for (int rf = 0; rf < 4; ++rf) {
      f32x4 v = {p2[rf][0], p2[rf][1], p2[rf][2], p2[rf][3]};
      *(f32x4*)(nbuf + wv * 64 + rf * 16 + lhi * 4) = v;
    }
  }
  __syncthreads();

  // coalesced P copy-out + norm reduce
  {
    short* Pg = Pws + (size_t)bb * 16384;
#pragma unroll
    for (int i = 0; i < 8; ++i) {
      int idx = tid + 256 * i;                // 16B chunk index
      int row = idx >> 5;
      int colb = (idx & 31) * 16;
      s16x8 v = *(const s16x8*)(smem + row * 512 + (colb ^ ((row & 7) << 4)));
      *(s16x8*)(Pg + idx * 8) = v;
    }
    if (tid < 64) {
      float s = nbuf[tid] + nbuf[64 + tid] + nbuf[128 + tid] + nbuf[192 + tid];
      norms_g[bb * 64 + tid] = s;
    }
  }
}

// ============ Kernel A (fallback): round-2 fused proj+cost ============
__global__ void __launch_bounds__(256, 2)
proj_cost_kernel(const float* __restrict__ slots_q, const float* __restrict__ slots_r,
                 const short* __restrict__ W1t, const short* __restrict__ W2t,
                 const float* __restrict__ b1, const float* __restrict__ b2,
                 float* __restrict__ out) {
  __shared__ char smem[65536];
  float* nbuf = (float*)smem;

  const int b    = blockIdx.x;
  const int tid  = threadIdx.x;
  const int wv   = tid >> 6;
  const int lane = tid & 63;
  const int l15  = lane & 15;
  const int lhi  = lane >> 4;

  {
    const float* sq = slots_q + (size_t)b * 16384;
    const float* sr = slots_r + (size_t)b * 16384;
#pragma unroll
    for (int i = 0; i < 32; ++i) {
      int idx4 = tid + 256 * i;
      int row = idx4 >> 6;
      int colb = (idx4 & 63) * 8;
      const float* src = (i < 16) ? (sq + idx4 * 4) : (sr + idx4 * 4 - 16384);
      float4 v = *(const float4*)src;
      unsigned lo = (unsigned)f2bf(v.x) | ((unsigned)f2bf(v.y) << 16);
      unsigned hi = (unsigned)f2bf(v.z) | ((unsigned)f2bf(v.w) << 16);
      *(uint2*)(smem + row * 512 + (colb ^ ((row & 7) << 4))) = make_uint2(lo, hi);
    }
  }
  __syncthreads();

  const int abase0 = l15 * 512;
  const int asw    = (l15 & 7) << 4;
  const int koff0  = lhi * 16;
  const short* wb1 = W1t + (wv * 64 + l15) * 256 + lhi * 8;
  const short* wb2 = W2t + (wv * 64 + l15) * 256 + lhi * 8;

  float b1v[4], b2v[4];
#pragma unroll
  for (int nf = 0; nf < 4; ++nf) {
    b1v[nf] = b1[wv * 64 + nf * 16 + l15];
    b2v[nf] = b2[wv * 64 + nf * 16 + l15];
  }

  const f32x4 z4 = {0.f, 0.f, 0.f, 0.f};
  f32x4 acc[8][4];

#pragma unroll
  for (int rf = 0; rf < 8; ++rf)
#pragma unroll
    for (int nf = 0; nf < 4; ++nf) acc[rf][nf] = z4;
  gemm_kloop<8>(wb1, smem, abase0, asw, koff0, acc);
  __syncthreads();
#pragma unroll
  for (int rf = 0; rf < 8; ++rf)
#pragma unroll
    for (int nf = 0; nf < 4; ++nf)
#pragma unroll
      for (int j = 0; j < 4; ++j) {
        int row = rf * 16 + lhi * 4 + j;
        int colb = (wv * 64 + nf * 16 + l15) * 2;
        *(unsigned short*)(smem + row * 512 + (colb ^ ((row & 7) << 4))) =
            f2bf(fmaxf(acc[rf][nf][j] + b1v[nf], 0.0f));
      }
  __syncthreads();

#pragma unroll
  for (int rf = 0; rf < 8; ++rf)
#pragma unroll
    for (int nf = 0; nf < 4; ++nf) acc[rf][nf] = z4;
  gemm_kloop<8>(wb2, smem, abase0, asw, koff0, acc);
  __syncthreads();

  float p2[8][4];
#pragma unroll
  for (int rf = 0; rf < 8; ++rf)
#pragma unroll
    for (int j = 0; j < 4; ++j) {
      float s = 0.0f;
#pragma unroll
      for (int nf = 0; nf < 4; ++nf) {
        unsigned short h = f2bf(acc[rf][nf][j] + b2v[nf]);
        int row = rf * 16 + lhi * 4 + j;
        int colb = (wv * 64 + nf * 16 + l15) * 2;
        *(unsigned short*)(smem + row * 512 + (colb ^ ((row & 7) << 4))) = h;
        float f = bf2f(h);
        s += f * f;
      }
      p2[rf][j] = s;
    }
#pragma unroll
  for (int d = 1; d < 16; d <<= 1)
#pragma unroll
    for (int rf = 0; rf < 8; ++rf)
#pragma unroll
      for (int j = 0; j < 4; ++j) p2[rf][j] += __shfl_xor(p2[rf][j], d);
  __syncthreads();

  f32x4 accC[4];
#pragma unroll
  for (int n = 0; n < 4; ++n) accC[n] = z4;
#pragma unroll
  for (int ks = 0; ks < 8; ++ks) {
    const int ko = (ks * 64 + koff0) ^ asw;
    s16x8 aQ = *(const s16x8*)(smem + wv * 8192 + abase0 + ko);
#pragma unroll
    for (int n = 0; n < 4; ++n) {
      s16x8 bR = *(const s16x8*)(smem + 32768 + n * 8192 + abase0 + ko);
      accC[n] = MFMA16(aQ, bR, accC[n]);
    }
  }
  __syncthreads();

  if (l15 == 0) {
#pragma unroll
    for (int rf = 0; rf < 8; ++rf) {
      f32x4 v = {p2[rf][0], p2[rf][1], p2[rf][2], p2[rf][3]};
      *(f32x4*)(nbuf + wv * 128 + rf * 16 + lhi * 4) = v;
    }
  }
  __syncthreads();

  f32x4 nq = z4;
#pragma unroll
  for (int w = 0; w < 4; ++w)
    nq += *(const f32x4*)(nbuf + w * 128 + wv * 16 + lhi * 4);
  float nR[4];
#pragma unroll
  for (int n = 0; n < 4; ++n) {
    float s = 0.0f;
#pragma unroll
    for (int w = 0; w < 4; ++w) s += nbuf[w * 128 + 64 + n * 16 + l15];
    nR[n] = s;
  }

  float* Cb = out + OFF_C + (size_t)b * 4096;
#pragma unroll
  for (int n = 0; n < 4; ++n)
#pragma unroll
    for (int j = 0; j < 4; ++j) {
      float d2 = nq[j] + nR[n] - 2.0f * accC[n][j];
      Cb[(wv * 16 + lhi * 4 + j) * 64 + n * 16 + l15] = sqrtf(fmaxf(d2, 0.0f));
    }
}

// ====== Kernel B: (MODE1: qr+cdist from P) + Sinkhorn + MESH + outputs ======
template <int MODE>
__global__ void __launch_bounds__(256, 4)
sinkhorn_solve_k(const float* __restrict__ mask_r, const short* __restrict__ Pws,
                 const float* __restrict__ norms_g, float* __restrict__ out) {
  __shared__ char bsm[32768];     // MODE1: Pr tile; then C/T tile [64][65] f32
  __shared__ float u_arr[64], w_arr[64], red[4];
  float* tile = (float*)bsm;

  const int b    = blockIdx.x;
  const int tid  = threadIdx.x;
  const int wv   = tid >> 6;
  const int lane = tid & 63;
  const int l15  = lane & 15;
  const int lhi  = lane >> 4;
  const int rk   = tid >> 2;
  const int g    = tid & 3;
  const int e0   = g * 16;

  if (tid < 64) w_arr[tid] = __logf(fmaxf(mask_r[(size_t)b * 64 + tid], 1e-8f));

  if (MODE == 0) {
    const float* Cb = out + OFF_C + (size_t)b * 4096;
#pragma unroll
    for (int i = 0; i < 16; ++i) {
      int idx = tid + 256 * i;
      tile[(idx >> 6) * 65 + (idx & 63)] = Cb[idx];
    }
    __syncthreads();
  } else {
    const short* Pq = Pws + (size_t)(2 * b) * 16384;
    const short* Pr = Pws + (size_t)(2 * b + 1) * 16384;
    // Pq A-frags straight from global (this wave's 16 rows only)
    s16x8 af[8];
#pragma unroll
    for (int ks = 0; ks < 8; ++ks)
      af[ks] = *(const s16x8*)(Pq + (wv * 16 + l15) * 256 + ks * 32 + lhi * 8);
    // stage Pr -> swizzled LDS tile
#pragma unroll
    for (int i = 0; i < 8; ++i) {
      int idx = tid + 256 * i;
      int row = idx >> 5;
      int colb = (idx & 31) * 16;
      *(s16x8*)(bsm + row * 512 + (colb ^ ((row & 7) << 4))) =
          *(const s16x8*)(Pr + idx * 8);
    }
    float q2v[4], r2v[4];
#pragma unroll
    for (int j = 0; j < 4; ++j)
      q2v[j] = norms_g[2 * b * 64 + wv * 16 + lhi * 4 + j];
#pragma unroll
    for (int n = 0; n < 4; ++n)
      r2v[n] = norms_g[(2 * b + 1) * 64 + n * 16 + l15];
    __syncthreads();

    const f32x4 z4 = {0.f, 0.f, 0.f, 0.f};
    f32x4 accC[4];
#pragma unroll
    for (int n = 0; n < 4; ++n) accC[n] = z4;
    const int asw = (l15 & 7) << 4;
#pragma unroll
    for (int ks = 0; ks < 8; ++ks) {
      const int ko = ks * 64 + lhi * 16;
#pragma unroll
      for (int n = 0; n < 4; ++n) {
        int row = n * 16 + l15;
        s16x8 bR = *(const s16x8*)(bsm + row * 512 + (ko ^ asw));
        accC[n] = MFMA16(af[ks], bR, accC[n]);
      }
    }
    __syncthreads();   // Pr reads done -> tile region free for C

#pragma unroll
    for (int n = 0; n < 4; ++n)
#pragma unroll
      for (int j = 0; j < 4; ++j) {
        int k = wv * 16 + lhi * 4 + j;
        int m = n * 16 + l15;
        float d2 = q2v[j] + r2v[n] - 2.0f * accC[n][j];
        tile[k * 65 + m] = sqrtf(fmaxf(d2, 0.0f));
      }
    __syncthreads();
    // C -> global (coalesced)
    float* Cb = out + OFF_C + (size_t)b * 4096;
#pragma unroll
    for (int i = 0; i < 16; ++i) {
      int idx = tid + 256 * i;
      Cb[idx] = tile[(idx >> 6) * 65 + (idx & 63)];
    }
  }

  // C slices into registers
  float cn[16], cc[16];
#pragma unroll
  for (int i = 0; i < 16; ++i) {
    cn[i] = tile[rk * 65 + e0 + i] * -20.0f;
    cc[i] = tile[(e0 + i) * 65 + rk] * -20.0f;
  }

  // ---------------- Sinkhorn ----------------
  for (int it = 0; it < 20; ++it) {
    {
      float v[16];
#pragma unroll
      for (int i = 0; i < 16; ++i) v[i] = cn[i] + w_arr[e0 + i];
      float mx = v[0];
#pragma unroll
      for (int i = 1; i < 16; ++i) mx = fmaxf(mx, v[i]);
      float s = 0.0f;
#pragma unroll
      for (int i = 0; i < 16; ++i) s += __expf(v[i] - mx);
#pragma unroll
      for (int d = 1; d < 4; d <<= 1) {
        float mo = __shfl_xor(mx, d), so = __shfl_xor(s, d);
        float nm = fmaxf(mx, mo);
        s = s * __expf(mx - nm) + so * __expf(mo - nm);
        mx = nm;
      }
      if (g == 0) u_arr[rk] = -(mx + __logf(s));
    }
    __syncthreads();
    {
      float v[16];
#pragma unroll
      for (int i = 0; i < 16; ++i) v[i] = cc[i] + u_arr[e0 + i];
      float mx = v[0];
#pragma unroll
      for (int i = 1; i < 16; ++i) mx = fmaxf(mx, v[i]);
      float s = 0.0f;
#pragma unroll
      for (int i = 0; i < 16; ++i) s += __expf(v[i] - mx);
#pragma unroll
      for (int d = 1; d < 4; d <<= 1) {
        float mo = __shfl_xor(mx, d), so = __shfl_xor(s, d);
        float nm = fmaxf(mx, mo);
        s = s * __expf(mx - nm) + so * __expf(mo - nm);
        mx = nm;
      }
      if (g == 0) w_arr[rk] = -(mx + __logf(s));
    }
    __syncthreads();
  }

  // ---------------- T = exp(cn + u + w), then MESH x3 ----------------
  float t[16];
  {
    float uk = u_arr[rk];
#pragma unroll
    for (int i = 0; i < 16; ++i) t[i] = __expf(cn[i] + uk + w_arr[e0 + i]);
  }
  for (int it = 0; it < 3; ++it) {
    if (it > 0) {
      __syncthreads();
#pragma unroll
      for (int i = 0; i < 16; ++i) t[i] = tile[rk * 65 + e0 + i];
    }
    float s = 0.0f;
#pragma unroll
    for (int i = 0; i < 16; ++i) { t[i] *= t[i]; s += t[i]; }
    s += __shfl_xor(s, 1); s += __shfl_xor(s, 2);
    float inv = 1.0f / (s + 1e-8f);
#pragma unroll
    for (int i = 0; i < 16; ++i) tile[rk * 65 + e0 + i] = t[i] * inv;
    __syncthreads();
    float tc[16]; float cs = 0.0f;
#pragma unroll
    for (int i = 0; i < 16; ++i) { tc[i] = tile[(e0 + i) * 65 + rk]; cs += tc[i]; }
    cs += __shfl_xor(cs, 1); cs += __shfl_xor(cs, 2);
    inv = 1.0f / (cs + 1e-8f);
#pragma unroll
    for (int i = 0; i < 16; ++i) tile[(e0 + i) * 65 + rk] = tc[i] * inv;
  }
  __syncthreads();

  // ---------------- transport cost + similarity + T store ----------------
  {
    float part = 0.0f;
#pragma unroll
    for (int i = 0; i < 16; ++i)
      part += tile[rk * 65 + e0 + i] * (cn[i] * -0.05f);
#pragma unroll
    for (int d = 1; d < 64; d <<= 1) part += __shfl_xor(part, d);
    if (lane == 0) red[wv] = part;
  }
  __syncthreads();
  if (tid == 0) {
    float tc = red[0] + red[1] + red[2] + red[3];
    out[OFF_TC + b] = tc;
    out[b] = 1.0f / (1.0f + __expf(tc));
  }
  {
    float* Tout = out + OFF_T + (size_t)b * 4096;
#pragma unroll
    for (int i = 0; i < 16; ++i) {
      int idx = tid + 256 * i;
      Tout[idx] = tile[(idx >> 6) * 65 + (idx & 63)];
    }
  }
}

extern "C" void kernel_launch(void* const* d_in, const int* in_sizes, int n_in,
                              void* d_out, int out_size, void* d_ws, size_t ws_size,
                              hipStream_t stream) {
  const float* slots_q = (const float*)d_in[0];
  const float* slots_r = (const float*)d_in[1];
  // d_in[2] = mask_q: cancels out of T/T_hard/C/cost (row-rescaling invariance).
  const float* mask_r = (const float*)d_in[3];
  const float* W1 = (const float*)d_in[4];
  const float* b1 = (const float*)d_in[5];
  const float* W2 = (const float*)d_in[6];
  const float* b2 = (const float*)d_in[7];

  short* W1t = (short*)d_ws;
  short* W2t = W1t + 65536;
  float* norms = (float*)((char*)d_ws + 262144);
  short* Pws = (short*)((char*)d_ws + 1310720);

  prep_w_kernel<<<256, 256, 0, stream>>>(W1, W2, W1t, W2t);
  if (ws_size >= WS_NEED) {
    proj_kernel<<<4096, 256, 0, stream>>>(slots_q, slots_r, W1t, W2t, b1, b2,
                                          Pws, norms);
    sinkhorn_solve_k<1><<<2048, 256, 0, stream>>>(mask_r, Pws, norms,
                                                  (float*)d_out);
  } else {
    proj_cost_kernel<<<2048, 256, 0, stream>>>(slots_q, slots_r, W1t, W2t, b1,
                                               b2, (float*)d_out);
    sinkhorn_solve_k<0><<<2048, 256, 0, stream>>>(mask_r, nullptr, nullptr,
                                                  (float*)d_out);
  }
}

// Round 5
// 277.228 us; speedup vs baseline: 1.1433x; 1.1433x over previous
//
#include <hip/hip_runtime.h>

// SinkhornOT — round 5: fragment-major packed W (each W-frag load = one
// coalesced 1KiB wave burst instead of a 16-line scatter) + depth-2 register
// prefetch, on the round-3 fused proj+cost structure (no P spill).
// B=2048, K=M=64, D=256, eps=0.05, 20 sinkhorn iters, 3 MESH iters.

typedef __attribute__((ext_vector_type(8))) short s16x8;
typedef __attribute__((ext_vector_type(4))) float f32x4;

#define OFF_T  2048
#define OFF_C  (2048 + 2048 * 4096)
#define OFF_TC (2048 + 2 * 2048 * 4096)

__device__ __forceinline__ unsigned short f2bf(float x) {  // RNE f32->bf16
  unsigned u = __builtin_bit_cast(unsigned, x);
  u += 0x7fffu + ((u >> 16) & 1u);
  return (unsigned short)(u >> 16);
}
__device__ __forceinline__ float bf2f(unsigned short h) {
  return __builtin_bit_cast(float, ((unsigned)h) << 16);
}

#define MFMA16(a, b, c) __builtin_amdgcn_mfma_f32_16x16x32_bf16((a), (b), (c), 0, 0, 0)

// Pack W (f32 [k][col] row-major) into fragment-major bf16:
// Wp[((cf*8 + ks)*64 + lane)*8 + ii] = W[k][col]
//   cf = col>>4, l15 = col&15, ks = k>>5, lhi = (k>>3)&3, ii = k&7,
//   lane = lhi*16 + l15.
// A wave's fragment (cf, ks) is then a contiguous 1024B burst (16B/lane).
__global__ void __launch_bounds__(256)
prep_w_kernel(const float* __restrict__ W1, const float* __restrict__ W2,
              short* __restrict__ W1p, short* __restrict__ W2p) {
  int i = blockIdx.x * 256 + threadIdx.x;   // 65536 threads exactly
  int k = i >> 8, col = i & 255;
  int p = (col >> 4) * 4096 + (k >> 5) * 512 +
          (((k >> 3) & 3) * 16 + (col & 15)) * 8 + (k & 7);
  W1p[p] = (short)f2bf(W1[i]);
  W2p[p] = (short)f2bf(W2[i]);
}

// K-loop: wave computes RF row-frags x its 4 col-frags. Packed-W fragments
// prefetched 2 k-steps ahead (3 static buffers; loop fully unrolled).
template <int RF>
__device__ __forceinline__ void gemm_kloop(const short* __restrict__ wb,
                                           const char* sm, int abase0, int asw,
                                           int koff0, f32x4 (&acc)[RF][4]) {
  s16x8 bw[3][4];
#pragma unroll
  for (int nf = 0; nf < 4; ++nf) bw[0][nf] = *(const s16x8*)(wb + nf * 4096);
#pragma unroll
  for (int nf = 0; nf < 4; ++nf) bw[1][nf] = *(const s16x8*)(wb + nf * 4096 + 512);
#pragma unroll
  for (int ks = 0; ks < 8; ++ks) {
    if (ks < 6) {
#pragma unroll
      for (int nf = 0; nf < 4; ++nf)
        bw[(ks + 2) % 3][nf] = *(const s16x8*)(wb + nf * 4096 + (ks + 2) * 512);
    }
    const int ko = (ks * 64 + koff0) ^ asw;
    s16x8 af[RF];
#pragma unroll
    for (int rf = 0; rf < RF; ++rf)
      af[rf] = *(const s16x8*)(sm + rf * 8192 + abase0 + ko);
#pragma unroll
    for (int rf = 0; rf < RF; ++rf)
#pragma unroll
      for (int nf = 0; nf < 4; ++nf)
        acc[rf][nf] = MFMA16(af[rf], bw[ks % 3][nf], acc[rf][nf]);
  }
}

// ======================= Kernel A: projections + cdist =======================
__global__ void __launch_bounds__(256, 2)
proj_cost_kernel(const float* __restrict__ slots_q, const float* __restrict__ slots_r,
                 const short* __restrict__ W1p, const short* __restrict__ W2p,
                 const float* __restrict__ b1, const float* __restrict__ b2,
                 float* __restrict__ out) {
  // [128 rows][512 B] swizzled bf16 tile: X -> H -> P (rows 0-63 Q, 64-127 R).
  // After qr-GEMM frees it, head reused as norm-partials buffer [4][128] f32.
  __shared__ char smem[65536];
  float* nbuf = (float*)smem;

  const int b    = blockIdx.x;
  const int tid  = threadIdx.x;
  const int wv   = tid >> 6;
  const int lane = tid & 63;
  const int l15  = lane & 15;
  const int lhi  = lane >> 4;

  // ---------- stage X (f32 -> bf16, swizzled) ----------
  {
    const float* sq = slots_q + (size_t)b * 16384;
    const float* sr = slots_r + (size_t)b * 16384;
#pragma unroll
    for (int i = 0; i < 32; ++i) {
      int idx4 = tid + 256 * i;               // float4 index, rows = idx4>>6
      int row = idx4 >> 6;                    // 0..127 (i<16 -> Q, else R)
      int colb = (idx4 & 63) * 8;
      const float* src = (i < 16) ? (sq + idx4 * 4) : (sr + idx4 * 4 - 16384);
      float4 v = *(const float4*)src;
      unsigned lo = (unsigned)f2bf(v.x) | ((unsigned)f2bf(v.y) << 16);
      unsigned hi = (unsigned)f2bf(v.z) | ((unsigned)f2bf(v.w) << 16);
      *(uint2*)(smem + row * 512 + (colb ^ ((row & 7) << 4))) = make_uint2(lo, hi);
    }
  }
  __syncthreads();

  const int abase0 = l15 * 512;          // A-frag lane row base (row = rf*16+l15)
  const int asw    = (l15 & 7) << 4;     // swizzle (row&7 == l15&7 for all frags)
  const int koff0  = lhi * 16;           // byte sub-offset within 64B k-step
  const short* wb1 = W1p + wv * 4 * 4096 + lane * 8;   // packed wave base
  const short* wb2 = W2p + wv * 4 * 4096 + lane * 8;

  float b1v[4], b2v[4];
#pragma unroll
  for (int nf = 0; nf < 4; ++nf) {
    b1v[nf] = b1[wv * 64 + nf * 16 + l15];
    b2v[nf] = b2[wv * 64 + nf * 16 + l15];
  }

  const f32x4 z4 = {0.f, 0.f, 0.f, 0.f};
  f32x4 acc[8][4];

  // ================= GEMM1: H = relu(X*W1 + b1) =================
#pragma unroll
  for (int rf = 0; rf < 8; ++rf)
#pragma unroll
    for (int nf = 0; nf < 4; ++nf) acc[rf][nf] = z4;
  gemm_kloop<8>(wb1, smem, abase0, asw, koff0, acc);
  __syncthreads();   // all waves done reading X
#pragma unroll
  for (int rf = 0; rf < 8; ++rf)
#pragma unroll
    for (int nf = 0; nf < 4; ++nf)
#pragma unroll
      for (int j = 0; j < 4; ++j) {
        int row = rf * 16 + lhi * 4 + j;
        int colb = (wv * 64 + nf * 16 + l15) * 2;
        *(unsigned short*)(smem + row * 512 + (colb ^ ((row & 7) << 4))) =
            f2bf(fmaxf(acc[rf][nf][j] + b1v[nf], 0.0f));
      }
  __syncthreads();

  // ================= GEMM2: P = H*W2 + b2 (+ norm partials) =================
#pragma unroll
  for (int rf = 0; rf < 8; ++rf)
#pragma unroll
    for (int nf = 0; nf < 4; ++nf) acc[rf][nf] = z4;
  gemm_kloop<8>(wb2, smem, abase0, asw, koff0, acc);
  __syncthreads();   // all waves done reading H

  float p2[8][4];
#pragma unroll
  for (int rf = 0; rf < 8; ++rf)
#pragma unroll
    for (int j = 0; j < 4; ++j) {
      float s = 0.0f;
#pragma unroll
      for (int nf = 0; nf < 4; ++nf) {
        unsigned short h = f2bf(acc[rf][nf][j] + b2v[nf]);
        int row = rf * 16 + lhi * 4 + j;
        int colb = (wv * 64 + nf * 16 + l15) * 2;
        *(unsigned short*)(smem + row * 512 + (colb ^ ((row & 7) << 4))) = h;
        float f = bf2f(h);
        s += f * f;
      }
      p2[rf][j] = s;
    }
#pragma unroll
  for (int d = 1; d < 16; d <<= 1)
#pragma unroll
    for (int rf = 0; rf < 8; ++rf)
#pragma unroll
      for (int j = 0; j < 4; ++j) p2[rf][j] += __shfl_xor(p2[rf][j], d);
  __syncthreads();   // P staged

  // ========= qr GEMM (M-split): qr[k][m] = sum_d Pq[k][d]*Pr[m][d] =========
  f32x4 accC[4];
#pragma unroll
  for (int n = 0; n < 4; ++n) accC[n] = z4;
#pragma unroll
  for (int ks = 0; ks < 8; ++ks) {
    const int ko = (ks * 64 + koff0) ^ asw;   // rows here also have row&7==l15&7
    s16x8 aQ = *(const s16x8*)(smem + wv * 8192 + abase0 + ko);
#pragma unroll
    for (int n = 0; n < 4; ++n) {
      s16x8 bR = *(const s16x8*)(smem + 32768 + n * 8192 + abase0 + ko);
      accC[n] = MFMA16(aQ, bR, accC[n]);
    }
  }
  __syncthreads();   // P reads done -> tile region free for norm exchange

  if (l15 == 0) {
#pragma unroll
    for (int rf = 0; rf < 8; ++rf) {
      f32x4 v = {p2[rf][0], p2[rf][1], p2[rf][2], p2[rf][3]};
      *(f32x4*)(nbuf + wv * 128 + rf * 16 + lhi * 4) = v;
    }
  }
  __syncthreads();

  f32x4 nq = z4;
#pragma unroll
  for (int w = 0; w < 4; ++w)
    nq += *(const f32x4*)(nbuf + w * 128 + wv * 16 + lhi * 4);
  float nR[4];
#pragma unroll
  for (int n = 0; n < 4; ++n) {
    float s = 0.0f;
#pragma unroll
    for (int w = 0; w < 4; ++w) s += nbuf[w * 128 + 64 + n * 16 + l15];
    nR[n] = s;
  }

  // C = sqrt(max(q2 + r2 - 2*qr, 0)) -> direct global store
  float* Cb = out + OFF_C + (size_t)b * 4096;
#pragma unroll
  for (int n = 0; n < 4; ++n)
#pragma unroll
    for (int j = 0; j < 4; ++j) {
      float d2 = nq[j] + nR[n] - 2.0f * accC[n][j];
      Cb[(wv * 16 + lhi * 4 + j) * 64 + n * 16 + l15] = sqrtf(fmaxf(d2, 0.0f));
    }
}

// ======================= Kernel B: Sinkhorn + MESH + outputs =======================
__global__ void __launch_bounds__(256, 4)
sinkhorn_solve(const float* __restrict__ mask_r, float* __restrict__ out) {
  __shared__ float tile[64 * 65];   // C load staging, then T tile for MESH
  __shared__ float u_arr[64], w_arr[64], red[4];

  const int b    = blockIdx.x;
  const int tid  = threadIdx.x;
  const int wv   = tid >> 6;
  const int lane = tid & 63;
  const int rk   = tid >> 2;    // row (or col) this thread group owns
  const int g    = tid & 3;     // 4-lane split of the 64-wide reduction
  const int e0   = g * 16;

  const float* Cb = out + OFF_C + (size_t)b * 4096;

  // load C coalesced -> LDS tile
#pragma unroll
  for (int i = 0; i < 16; ++i) {
    int idx = tid + 256 * i;
    tile[(idx >> 6) * 65 + (idx & 63)] = Cb[idx];
  }
  if (tid < 64) w_arr[tid] = __logf(fmaxf(mask_r[(size_t)b * 64 + tid], 1e-8f));
  __syncthreads();

  // C slices into registers: cn = row slice * (-1/eps), cc = col slice * (-1/eps)
  float cn[16], cc[16];
#pragma unroll
  for (int i = 0; i < 16; ++i) {
    cn[i] = tile[rk * 65 + e0 + i] * -20.0f;
    cc[i] = tile[(e0 + i) * 65 + rk] * -20.0f;
  }

  // ---------------- Sinkhorn: u = -lse_m(cn + w); w = -lse_k(cc + u) ----------------
  for (int it = 0; it < 20; ++it) {
    {
      float v[16];
#pragma unroll
      for (int i = 0; i < 16; ++i) v[i] = cn[i] + w_arr[e0 + i];
      float mx = v[0];
#pragma unroll
      for (int i = 1; i < 16; ++i) mx = fmaxf(mx, v[i]);
      float s = 0.0f;
#pragma unroll
      for (int i = 0; i < 16; ++i) s += __expf(v[i] - mx);
#pragma unroll
      for (int d = 1; d < 4; d <<= 1) {
        float mo = __shfl_xor(mx, d), so = __shfl_xor(s, d);
        float nm = fmaxf(mx, mo);
        s = s * __expf(mx - nm) + so * __expf(mo - nm);
        mx = nm;
      }
      if (g == 0) u_arr[rk] = -(mx + __logf(s));
    }
    __syncthreads();
    {
      float v[16];
#pragma unroll
      for (int i = 0; i < 16; ++i) v[i] = cc[i] + u_arr[e0 + i];
      float mx = v[0];
#pragma unroll
      for (int i = 1; i < 16; ++i) mx = fmaxf(mx, v[i]);
      float s = 0.0f;
#pragma unroll
      for (int i = 0; i < 16; ++i) s += __expf(v[i] - mx);
#pragma unroll
      for (int d = 1; d < 4; d <<= 1) {
        float mo = __shfl_xor(mx, d), so = __shfl_xor(s, d);
        float nm = fmaxf(mx, mo);
        s = s * __expf(mx - nm) + so * __expf(mo - nm);
        mx = nm;
      }
      if (g == 0) w_arr[rk] = -(mx + __logf(s));
    }
    __syncthreads();
  }

  // ---------------- T = exp(cn + u + w), then MESH x3 ----------------
  float t[16];
  {
    float uk = u_arr[rk];
#pragma unroll
    for (int i = 0; i < 16; ++i) t[i] = __expf(cn[i] + uk + w_arr[e0 + i]);
  }
  for (int it = 0; it < 3; ++it) {
    if (it > 0) {
      __syncthreads();
#pragma unroll
      for (int i = 0; i < 16; ++i) t[i] = tile[rk * 65 + e0 + i];
    }
    // row: square + normalize by rowsum
    float s = 0.0f;
#pragma unroll
    for (int i = 0; i < 16; ++i) { t[i] *= t[i]; s += t[i]; }
    s += __shfl_xor(s, 1); s += __shfl_xor(s, 2);
    float inv = 1.0f / (s + 1e-8f);
#pragma unroll
    for (int i = 0; i < 16; ++i) tile[rk * 65 + e0 + i] = t[i] * inv;
    __syncthreads();
    // col: normalize by colsum
    float tc[16]; float cs = 0.0f;
#pragma unroll
    for (int i = 0; i < 16; ++i) { tc[i] = tile[(e0 + i) * 65 + rk]; cs += tc[i]; }
    cs += __shfl_xor(cs, 1); cs += __shfl_xor(cs, 2);
    inv = 1.0f / (cs + 1e-8f);
#pragma unroll
    for (int i = 0; i < 16; ++i) tile[(e0 + i) * 65 + rk] = tc[i] * inv;
  }
  __syncthreads();

  // ---------------- transport cost + similarity + T store ----------------
  {
    float part = 0.0f;
#pragma unroll
    for (int i = 0; i < 16; ++i)
      part += tile[rk * 65 + e0 + i] * (cn[i] * -0.05f);
#pragma unroll
    for (int d = 1; d < 64; d <<= 1) part += __shfl_xor(part, d);
    if (lane == 0) red[wv] = part;
  }
  __syncthreads();
  if (tid == 0) {
    float tc = red[0] + red[1] + red[2] + red[3];
    out[OFF_TC + b] = tc;
    out[b] = 1.0f / (1.0f + __expf(tc));
  }
  {
    float* Tout = out + OFF_T + (size_t)b * 4096;
#pragma unroll
    for (int i = 0; i < 16; ++i) {
      int idx = tid + 256 * i;
      Tout[idx] = tile[(idx >> 6) * 65 + (idx & 63)];
    }
  }
}

extern "C" void kernel_launch(void* const* d_in, const int* in_sizes, int n_in,
                              void* d_out, int out_size, void* d_ws, size_t ws_size,
                              hipStream_t stream) {
  const float* slots_q = (const float*)d_in[0];
  const float* slots_r = (const float*)d_in[1];
  // d_in[2] = mask_q: cancels out of T/T_hard/C/cost (row-rescaling invariance).
  const float* mask_r = (const float*)d_in[3];
  const float* W1 = (const float*)d_in[4];
  const float* b1 = (const float*)d_in[5];
  const float* W2 = (const float*)d_in[6];
  const float* b2 = (const float*)d_in[7];

  short* W1p = (short*)d_ws;            // fragment-major packed bf16 weights
  short* W2p = W1p + 65536;

  prep_w_kernel<<<256, 256, 0, stream>>>(W1, W2, W1p, W2p);
  proj_cost_kernel<<<2048, 256, 0, stream>>>(slots_q, slots_r, W1p, W2p, b1, b2,
                                             (float*)d_out);
  sinkhorn_solve<<<2048, 256, 0, stream>>>(mask_r, (float*)d_out);
}

// Round 6
// 255.051 us; speedup vs baseline: 1.2427x; 1.0870x over previous
//
#include <hip/hip_runtime.h>

// SinkhornOT — round 6: operand-swapped projection GEMMs (acc j-direction ==
// LDS k-contiguous direction -> 8B vector epilogue writes) + v_cvt_pk_bf16_f32
// for all f32->bf16. Cuts ~6000 VALU instr/thread to ~1600.
// B=2048, K=M=64, D=256, eps=0.05, 20 sinkhorn iters, 3 MESH iters.

typedef __attribute__((ext_vector_type(8))) short s16x8;
typedef __attribute__((ext_vector_type(4))) float f32x4;

#define OFF_T  2048
#define OFF_C  (2048 + 2048 * 4096)
#define OFF_TC (2048 + 2 * 2048 * 4096)

__device__ __forceinline__ unsigned short f2bf(float x) {  // RNE f32->bf16
  unsigned u = __builtin_bit_cast(unsigned, x);
  u += 0x7fffu + ((u >> 16) & 1u);
  return (unsigned short)(u >> 16);
}
__device__ __forceinline__ unsigned cvtpk(float lo, float hi) {
  unsigned r;
  asm("v_cvt_pk_bf16_f32 %0, %1, %2" : "=v"(r) : "v"(lo), "v"(hi));
  return r;
}

#define MFMA16(a, b, c) __builtin_amdgcn_mfma_f32_16x16x32_bf16((a), (b), (c), 0, 0, 0)

// Pack W (f32 [k][col] row-major) into fragment-major bf16:
// fragment (cf=col>>4, ks=k>>5) is a contiguous 1KiB burst, 16B/lane,
// lane = ((k>>3)&3)*16 + (col&15), byte ii = k&7. This layout serves as the
// MFMA A-operand (row=col-of-W, k contiguous) for the swapped GEMMs.
__global__ void __launch_bounds__(256)
prep_w_kernel(const float* __restrict__ W1, const float* __restrict__ W2,
              short* __restrict__ W1p, short* __restrict__ W2p) {
  int i = blockIdx.x * 256 + threadIdx.x;   // 65536 threads exactly
  int k = i >> 8, col = i & 255;
  int p = (col >> 4) * 4096 + (k >> 5) * 512 +
          (((k >> 3) & 3) * 16 + (col & 15)) * 8 + (k & 7);
  W1p[p] = (short)f2bf(W1[i]);
  W2p[p] = (short)f2bf(W2[i]);
}

// K-loop, operand-swapped: acc[ef][rf] holds D[e=wv*64+ef*16+lhi*4+j]
// [r=rf*16+l15] (i.e. output transposed into k-contiguous-friendly form).
// A = packed W frag (prefetched 2 deep), B = X/H row frag from LDS.
template <int RF>
__device__ __forceinline__ void gemm_kloop(const short* __restrict__ wb,
                                           const char* sm, int abase0, int asw,
                                           int koff0, f32x4 (&acc)[4][RF]) {
  s16x8 bw[3][4];
#pragma unroll
  for (int nf = 0; nf < 4; ++nf) bw[0][nf] = *(const s16x8*)(wb + nf * 4096);
#pragma unroll
  for (int nf = 0; nf < 4; ++nf) bw[1][nf] = *(const s16x8*)(wb + nf * 4096 + 512);
#pragma unroll
  for (int ks = 0; ks < 8; ++ks) {
    if (ks < 6) {
#pragma unroll
      for (int nf = 0; nf < 4; ++nf)
        bw[(ks + 2) % 3][nf] = *(const s16x8*)(wb + nf * 4096 + (ks + 2) * 512);
    }
    const int ko = (ks * 64 + koff0) ^ asw;
    s16x8 af[RF];
#pragma unroll
    for (int rf = 0; rf < RF; ++rf)
      af[rf] = *(const s16x8*)(sm + rf * 8192 + abase0 + ko);
#pragma unroll
    for (int rf = 0; rf < RF; ++rf)
#pragma unroll
      for (int nf = 0; nf < 4; ++nf)
        acc[nf][rf] = MFMA16(bw[ks % 3][nf], af[rf], acc[nf][rf]);
  }
}

// ======================= Kernel A: projections + cdist =======================
__global__ void __launch_bounds__(256, 2)
proj_cost_kernel(const float* __restrict__ slots_q, const float* __restrict__ slots_r,
                 const short* __restrict__ W1p, const short* __restrict__ W2p,
                 const float* __restrict__ b1, const float* __restrict__ b2,
                 float* __restrict__ out) {
  // [128 rows][512 B] swizzled bf16 tile: X -> H -> P (rows 0-63 Q, 64-127 R).
  // After qr-GEMM frees it, head reused as norm-partials buffer [4][128] f32.
  __shared__ char smem[65536];
  float* nbuf = (float*)smem;

  const int b    = blockIdx.x;
  const int tid  = threadIdx.x;
  const int wv   = tid >> 6;
  const int lane = tid & 63;
  const int l15  = lane & 15;
  const int lhi  = lane >> 4;

  // ---------- stage X (f32 -> bf16 via cvt_pk, swizzled) ----------
  {
    const float* sq = slots_q + (size_t)b * 16384;
    const float* sr = slots_r + (size_t)b * 16384;
#pragma unroll
    for (int i = 0; i < 32; ++i) {
      int idx4 = tid + 256 * i;               // float4 index, rows = idx4>>6
      int row = idx4 >> 6;                    // 0..127 (i<16 -> Q, else R)
      int colb = (idx4 & 63) * 8;
      const float* src = (i < 16) ? (sq + idx4 * 4) : (sr + idx4 * 4 - 16384);
      float4 v = *(const float4*)src;
      *(uint2*)(smem + row * 512 + (colb ^ ((row & 7) << 4))) =
          make_uint2(cvtpk(v.x, v.y), cvtpk(v.z, v.w));
    }
  }
  __syncthreads();

  const int abase0 = l15 * 512;          // B-frag lane row base (row = rf*16+l15)
  const int asw    = (l15 & 7) << 4;     // swizzle (row&7 == l15&7 for all frags)
  const int koff0  = lhi * 16;           // byte sub-offset within 64B k-step
  const short* wb1 = W1p + wv * 4 * 4096 + lane * 8;   // packed wave base
  const short* wb2 = W2p + wv * 4 * 4096 + lane * 8;

  // bias per (ef, j): e = wv*64 + ef*16 + lhi*4 + j
  float4 b1v[4], b2v[4];
#pragma unroll
  for (int ef = 0; ef < 4; ++ef) {
    b1v[ef] = *(const float4*)(b1 + wv * 64 + ef * 16 + lhi * 4);
    b2v[ef] = *(const float4*)(b2 + wv * 64 + ef * 16 + lhi * 4);
  }

  const f32x4 z4 = {0.f, 0.f, 0.f, 0.f};
  f32x4 acc[4][8];

  // ================= GEMM1: H = relu(X*W1 + b1) =================
#pragma unroll
  for (int ef = 0; ef < 4; ++ef)
#pragma unroll
    for (int rf = 0; rf < 8; ++rf) acc[ef][rf] = z4;
  gemm_kloop<8>(wb1, smem, abase0, asw, koff0, acc);
  __syncthreads();   // all waves done reading X
  // write H: per (ef,rf) lane holds 4 consecutive e for row rf*16+l15 -> b64
#pragma unroll
  for (int ef = 0; ef < 4; ++ef) {
    const int eb = (wv * 64 + ef * 16 + lhi * 4) * 2;
#pragma unroll
    for (int rf = 0; rf < 8; ++rf) {
      float a0 = fmaxf(acc[ef][rf][0] + b1v[ef].x, 0.0f);
      float a1 = fmaxf(acc[ef][rf][1] + b1v[ef].y, 0.0f);
      float a2 = fmaxf(acc[ef][rf][2] + b1v[ef].z, 0.0f);
      float a3 = fmaxf(acc[ef][rf][3] + b1v[ef].w, 0.0f);
      *(uint2*)(smem + rf * 8192 + abase0 + (eb ^ asw)) =
          make_uint2(cvtpk(a0, a1), cvtpk(a2, a3));
    }
  }
  __syncthreads();

  // ================= GEMM2: P = H*W2 + b2 (+ f32 norm partials) =================
#pragma unroll
  for (int ef = 0; ef < 4; ++ef)
#pragma unroll
    for (int rf = 0; rf < 8; ++rf) acc[ef][rf] = z4;
  gemm_kloop<8>(wb2, smem, abase0, asw, koff0, acc);
  __syncthreads();   // all waves done reading H

  float pn[8] = {0.f, 0.f, 0.f, 0.f, 0.f, 0.f, 0.f, 0.f};
#pragma unroll
  for (int ef = 0; ef < 4; ++ef) {
    const int eb = (wv * 64 + ef * 16 + lhi * 4) * 2;
#pragma unroll
    for (int rf = 0; rf < 8; ++rf) {
      float a0 = acc[ef][rf][0] + b1v[0].x * 0.0f + b2v[ef].x;  // keep simple adds
      float a1 = acc[ef][rf][1] + b2v[ef].y;
      float a2 = acc[ef][rf][2] + b2v[ef].z;
      float a3 = acc[ef][rf][3] + b2v[ef].w;
      pn[rf] += a0 * a0 + a1 * a1 + a2 * a2 + a3 * a3;
      *(uint2*)(smem + rf * 8192 + abase0 + (eb ^ asw)) =
          make_uint2(cvtpk(a0, a1), cvtpk(a2, a3));
    }
  }
  // reduce norm partials over the 4 lanes sharing l15 (lhi = 0..3)
#pragma unroll
  for (int rf = 0; rf < 8; ++rf) {
    pn[rf] += __shfl_xor(pn[rf], 16);
    pn[rf] += __shfl_xor(pn[rf], 32);
  }
  __syncthreads();   // P staged

  // ========= qr GEMM (M-split): qr[k][m] = sum_d Pq[k][d]*Pr[m][d] =========
  f32x4 accC[4];
#pragma unroll
  for (int n = 0; n < 4; ++n) accC[n] = z4;
#pragma unroll
  for (int ks = 0; ks < 8; ++ks) {
    const int ko = (ks * 64 + koff0) ^ asw;
    s16x8 aQ = *(const s16x8*)(smem + wv * 8192 + abase0 + ko);
#pragma unroll
    for (int n = 0; n < 4; ++n) {
      s16x8 bR = *(const s16x8*)(smem + 32768 + n * 8192 + abase0 + ko);
      accC[n] = MFMA16(aQ, bR, accC[n]);
    }
  }
  __syncthreads();   // P reads done -> tile region free for norm exchange

  // nbuf[wv*128 + row] = this wave's 64-col partial for row
  if (lhi == 0) {
#pragma unroll
    for (int rf = 0; rf < 8; ++rf) nbuf[wv * 128 + rf * 16 + l15] = pn[rf];
  }
  __syncthreads();

  f32x4 nq = z4;
#pragma unroll
  for (int w = 0; w < 4; ++w)
    nq += *(const f32x4*)(nbuf + w * 128 + wv * 16 + lhi * 4);
  float nR[4];
#pragma unroll
  for (int n = 0; n < 4; ++n) {
    float s = 0.0f;
#pragma unroll
    for (int w = 0; w < 4; ++w) s += nbuf[w * 128 + 64 + n * 16 + l15];
    nR[n] = s;
  }

  // C = sqrt(max(q2 + r2 - 2*qr, 0)) -> direct global store
  float* Cb = out + OFF_C + (size_t)b * 4096;
#pragma unroll
  for (int n = 0; n < 4; ++n)
#pragma unroll
    for (int j = 0; j < 4; ++j) {
      float d2 = nq[j] + nR[n] - 2.0f * accC[n][j];
      Cb[(wv * 16 + lhi * 4 + j) * 64 + n * 16 + l15] = sqrtf(fmaxf(d2, 0.0f));
    }
}

// ======================= Kernel B: Sinkhorn + MESH + outputs =======================
__global__ void __launch_bounds__(256, 4)
sinkhorn_solve(const float* __restrict__ mask_r, float* __restrict__ out) {
  __shared__ float tile[64 * 65];   // C load staging, then T tile for MESH
  __shared__ float u_arr[64], w_arr[64], red[4];

  const int b    = blockIdx.x;
  const int tid  = threadIdx.x;
  const int wv   = tid >> 6;
  const int lane = tid & 63;
  const int rk   = tid >> 2;    // row (or col) this thread group owns
  const int g    = tid & 3;     // 4-lane split of the 64-wide reduction
  const int e0   = g * 16;

  const float* Cb = out + OFF_C + (size_t)b * 4096;

  // load C coalesced -> LDS tile
#pragma unroll
  for (int i = 0; i < 16; ++i) {
    int idx = tid + 256 * i;
    tile[(idx >> 6) * 65 + (idx & 63)] = Cb[idx];
  }
  if (tid < 64) w_arr[tid] = __logf(fmaxf(mask_r[(size_t)b * 64 + tid], 1e-8f));
  __syncthreads();

  // C slices into registers: cn = row slice * (-1/eps), cc = col slice * (-1/eps)
  float cn[16], cc[16];
#pragma unroll
  for (int i = 0; i < 16; ++i) {
    cn[i] = tile[rk * 65 + e0 + i] * -20.0f;
    cc[i] = tile[(e0 + i) * 65 + rk] * -20.0f;
  }

  // ---------------- Sinkhorn: u = -lse_m(cn + w); w = -lse_k(cc + u) ----------------
  for (int it = 0; it < 20; ++it) {
    {
      float v[16];
#pragma unroll
      for (int i = 0; i < 16; ++i) v[i] = cn[i] + w_arr[e0 + i];
      float mx = v[0];
#pragma unroll
      for (int i = 1; i < 16; ++i) mx = fmaxf(mx, v[i]);
      float s = 0.0f;
#pragma unroll
      for (int i = 0; i < 16; ++i) s += __expf(v[i] - mx);
#pragma unroll
      for (int d = 1; d < 4; d <<= 1) {
        float mo = __shfl_xor(mx, d), so = __shfl_xor(s, d);
        float nm = fmaxf(mx, mo);
        s = s * __expf(mx - nm) + so * __expf(mo - nm);
        mx = nm;
      }
      if (g == 0) u_arr[rk] = -(mx + __logf(s));
    }
    __syncthreads();
    {
      float v[16];
#pragma unroll
      for (int i = 0; i < 16; ++i) v[i] = cc[i] + u_arr[e0 + i];
      float mx = v[0];
#pragma unroll
      for (int i = 1; i < 16; ++i) mx = fmaxf(mx, v[i]);
      float s = 0.0f;
#pragma unroll
      for (int i = 0; i < 16; ++i) s += __expf(v[i] - mx);
#pragma unroll
      for (int d = 1; d < 4; d <<= 1) {
        float mo = __shfl_xor(mx, d), so = __shfl_xor(s, d);
        float nm = fmaxf(mx, mo);
        s = s * __expf(mx - nm) + so * __expf(mo - nm);
        mx = nm;
      }
      if (g == 0) w_arr[rk] = -(mx + __logf(s));
    }
    __syncthreads();
  }

  // ---------------- T = exp(cn + u + w), then MESH x3 ----------------
  float t[16];
  {
    float uk = u_arr[rk];
#pragma unroll
    for (int i = 0; i < 16; ++i) t[i] = __expf(cn[i] + uk + w_arr[e0 + i]);
  }
  for (int it = 0; it < 3; ++it) {
    if (it > 0) {
      __syncthreads();
#pragma unroll
      for (int i = 0; i < 16; ++i) t[i] = tile[rk * 65 + e0 + i];
    }
    // row: square + normalize by rowsum
    float s = 0.0f;
#pragma unroll
    for (int i = 0; i < 16; ++i) { t[i] *= t[i]; s += t[i]; }
    s += __shfl_xor(s, 1); s += __shfl_xor(s, 2);
    float inv = 1.0f / (s + 1e-8f);
#pragma unroll
    for (int i = 0; i < 16; ++i) tile[rk * 65 + e0 + i] = t[i] * inv;
    __syncthreads();
    // col: normalize by colsum
    float tc[16]; float cs = 0.0f;
#pragma unroll
    for (int i = 0; i < 16; ++i) { tc[i] = tile[(e0 + i) * 65 + rk]; cs += tc[i]; }
    cs += __shfl_xor(cs, 1); cs += __shfl_xor(cs, 2);
    inv = 1.0f / (cs + 1e-8f);
#pragma unroll
    for (int i = 0; i < 16; ++i) tile[(e0 + i) * 65 + rk] = tc[i] * inv;
  }
  __syncthreads();

  // ---------------- transport cost + similarity + T store ----------------
  {
    float part = 0.0f;
#pragma unroll
    for (int i = 0; i < 16; ++i)
      part += tile[rk * 65 + e0 + i] * (cn[i] * -0.05f);
#pragma unroll
    for (int d = 1; d < 64; d <<= 1) part += __shfl_xor(part, d);
    if (lane == 0) red[wv] = part;
  }
  __syncthreads();
  if (tid == 0) {
    float tc = red[0] + red[1] + red[2] + red[3];
    out[OFF_TC + b] = tc;
    out[b] = 1.0f / (1.0f + __expf(tc));
  }
  {
    float* Tout = out + OFF_T + (size_t)b * 4096;
#pragma unroll
    for (int i = 0; i < 16; ++i) {
      int idx = tid + 256 * i;
      Tout[idx] = tile[(idx >> 6) * 65 + (idx & 63)];
    }
  }
}

extern "C" void kernel_launch(void* const* d_in, const int* in_sizes, int n_in,
                              void* d_out, int out_size, void* d_ws, size_t ws_size,
                              hipStream_t stream) {
  const float* slots_q = (const float*)d_in[0];
  const float* slots_r = (const float*)d_in[1];
  // d_in[2] = mask_q: cancels out of T/T_hard/C/cost (row-rescaling invariance).
  const float* mask_r = (const float*)d_in[3];
  const float* W1 = (const float*)d_in[4];
  const float* b1 = (const float*)d_in[5];
  const float* W2 = (const float*)d_in[6];
  const float* b2 = (const float*)d_in[7];

  short* W1p = (short*)d_ws;            // fragment-major packed bf16 weights
  short* W2p = W1p + 65536;

  prep_w_kernel<<<256, 256, 0, stream>>>(W1, W2, W1p, W2p);
  proj_cost_kernel<<<2048, 256, 0, stream>>>(slots_q, slots_r, W1p, W2p, b1, b2,
                                             (float*)d_out);
  sinkhorn_solve<<<2048, 256, 0, stream>>>(mask_r, (float*)d_out);
}

// Round 7
// 244.637 us; speedup vs baseline: 1.2956x; 1.0426x over previous
//
#include <hip/hip_runtime.h>

// SinkhornOT — round 7: depth-4 W prefetch ring (covers L2/L3 latency) +
// two-phase MLP-batched X staging (16 float4 in flight before any LDS write).
// B=2048, K=M=64, D=256, eps=0.05, 20 sinkhorn iters, 3 MESH iters.

typedef __attribute__((ext_vector_type(8))) short s16x8;
typedef __attribute__((ext_vector_type(4))) float f32x4;

#define OFF_T  2048
#define OFF_C  (2048 + 2048 * 4096)
#define OFF_TC (2048 + 2 * 2048 * 4096)

__device__ __forceinline__ unsigned short f2bf(float x) {  // RNE f32->bf16
  unsigned u = __builtin_bit_cast(unsigned, x);
  u += 0x7fffu + ((u >> 16) & 1u);
  return (unsigned short)(u >> 16);
}
__device__ __forceinline__ unsigned cvtpk(float lo, float hi) {
  unsigned r;
  asm("v_cvt_pk_bf16_f32 %0, %1, %2" : "=v"(r) : "v"(lo), "v"(hi));
  return r;
}

#define MFMA16(a, b, c) __builtin_amdgcn_mfma_f32_16x16x32_bf16((a), (b), (c), 0, 0, 0)

// Pack W (f32 [k][col] row-major) into fragment-major bf16: fragment
// (cf=col>>4, ks=k>>5) is a contiguous 1KiB burst, 16B/lane,
// lane = ((k>>3)&3)*16 + (col&15), byte ii = k&7. Serves as the MFMA
// A-operand (row=col-of-W, k contiguous) for the operand-swapped GEMMs.
__global__ void __launch_bounds__(256)
prep_w_kernel(const float* __restrict__ W1, const float* __restrict__ W2,
              short* __restrict__ W1p, short* __restrict__ W2p) {
  int i = blockIdx.x * 256 + threadIdx.x;   // 65536 threads exactly
  int k = i >> 8, col = i & 255;
  int p = (col >> 4) * 4096 + (k >> 5) * 512 +
          (((k >> 3) & 3) * 16 + (col & 15)) * 8 + (k & 7);
  W1p[p] = (short)f2bf(W1[i]);
  W2p[p] = (short)f2bf(W2[i]);
}

// K-loop, operand-swapped: acc[nf][rf] holds D[e][r]. A = packed W frag
// (depth-4 register ring), B = X/H row frag from LDS.
template <int RF>
__device__ __forceinline__ void gemm_kloop(const short* __restrict__ wb,
                                           const char* sm, int abase0, int asw,
                                           int koff0, f32x4 (&acc)[4][RF]) {
  s16x8 bw[4][4];                 // 4-deep ring x 4 col-frags
#pragma unroll
  for (int p = 0; p < 4; ++p)
#pragma unroll
    for (int nf = 0; nf < 4; ++nf)
      bw[p][nf] = *(const s16x8*)(wb + nf * 4096 + p * 512);
#pragma unroll
  for (int ks = 0; ks < 8; ++ks) {
    const int ko = (ks * 64 + koff0) ^ asw;
    s16x8 af[RF];
#pragma unroll
    for (int rf = 0; rf < RF; ++rf)
      af[rf] = *(const s16x8*)(sm + rf * 8192 + abase0 + ko);
#pragma unroll
    for (int rf = 0; rf < RF; ++rf)
#pragma unroll
      for (int nf = 0; nf < 4; ++nf)
        acc[nf][rf] = MFMA16(bw[ks & 3][nf], af[rf], acc[nf][rf]);
    if (ks < 4) {                 // refill the slot just consumed, +4 ahead
#pragma unroll
      for (int nf = 0; nf < 4; ++nf)
        bw[ks & 3][nf] = *(const s16x8*)(wb + nf * 4096 + (ks + 4) * 512);
    }
  }
}

// ======================= Kernel A: projections + cdist =======================
__global__ void __launch_bounds__(256, 2)
proj_cost_kernel(const float* __restrict__ slots_q, const float* __restrict__ slots_r,
                 const short* __restrict__ W1p, const short* __restrict__ W2p,
                 const float* __restrict__ b1, const float* __restrict__ b2,
                 float* __restrict__ out) {
  // [128 rows][512 B] swizzled bf16 tile: X -> H -> P (rows 0-63 Q, 64-127 R).
  // After qr-GEMM frees it, head reused as norm-partials buffer [4][128] f32.
  __shared__ char smem[65536];
  float* nbuf = (float*)smem;

  const int b    = blockIdx.x;
  const int tid  = threadIdx.x;
  const int wv   = tid >> 6;
  const int lane = tid & 63;
  const int l15  = lane & 15;
  const int lhi  = lane >> 4;

  // ---------- stage X: 16 loads in flight, then convert+write (x2) ----------
  {
    const float* sq = slots_q + (size_t)b * 16384;
    const float* sr = slots_r + (size_t)b * 16384;
#pragma unroll
    for (int half = 0; half < 2; ++half) {
      float4 tmp[16];
#pragma unroll
      for (int i = 0; i < 16; ++i) {
        int idx4 = tid + 256 * (half * 16 + i);
        tmp[i] = (half == 0) ? *(const float4*)(sq + idx4 * 4)
                             : *(const float4*)(sr + (idx4 - 4096) * 4);
      }
#pragma unroll
      for (int i = 0; i < 16; ++i) {
        int idx4 = tid + 256 * (half * 16 + i);
        int row = idx4 >> 6;                  // 0..127
        int colb = (idx4 & 63) * 8;
        *(uint2*)(smem + row * 512 + (colb ^ ((row & 7) << 4))) =
            make_uint2(cvtpk(tmp[i].x, tmp[i].y), cvtpk(tmp[i].z, tmp[i].w));
      }
    }
  }
  __syncthreads();

  const int abase0 = l15 * 512;          // B-frag lane row base (row = rf*16+l15)
  const int asw    = (l15 & 7) << 4;     // swizzle (row&7 == l15&7 for all frags)
  const int koff0  = lhi * 16;           // byte sub-offset within 64B k-step
  const short* wb1 = W1p + wv * 4 * 4096 + lane * 8;   // packed wave base
  const short* wb2 = W2p + wv * 4 * 4096 + lane * 8;

  // bias per (ef, j): e = wv*64 + ef*16 + lhi*4 + j
  float4 b1v[4], b2v[4];
#pragma unroll
  for (int ef = 0; ef < 4; ++ef) {
    b1v[ef] = *(const float4*)(b1 + wv * 64 + ef * 16 + lhi * 4);
    b2v[ef] = *(const float4*)(b2 + wv * 64 + ef * 16 + lhi * 4);
  }

  const f32x4 z4 = {0.f, 0.f, 0.f, 0.f};
  f32x4 acc[4][8];

  // ================= GEMM1: H = relu(X*W1 + b1) =================
#pragma unroll
  for (int ef = 0; ef < 4; ++ef)
#pragma unroll
    for (int rf = 0; rf < 8; ++rf) acc[ef][rf] = z4;
  gemm_kloop<8>(wb1, smem, abase0, asw, koff0, acc);
  __syncthreads();   // all waves done reading X
  // write H: per (ef,rf) lane holds 4 consecutive e for row rf*16+l15 -> b64
#pragma unroll
  for (int ef = 0; ef < 4; ++ef) {
    const int eb = (wv * 64 + ef * 16 + lhi * 4) * 2;
#pragma unroll
    for (int rf = 0; rf < 8; ++rf) {
      float a0 = fmaxf(acc[ef][rf][0] + b1v[ef].x, 0.0f);
      float a1 = fmaxf(acc[ef][rf][1] + b1v[ef].y, 0.0f);
      float a2 = fmaxf(acc[ef][rf][2] + b1v[ef].z, 0.0f);
      float a3 = fmaxf(acc[ef][rf][3] + b1v[ef].w, 0.0f);
      *(uint2*)(smem + rf * 8192 + abase0 + (eb ^ asw)) =
          make_uint2(cvtpk(a0, a1), cvtpk(a2, a3));
    }
  }
  __syncthreads();

  // ================= GEMM2: P = H*W2 + b2 (+ f32 norm partials) =================
#pragma unroll
  for (int ef = 0; ef < 4; ++ef)
#pragma unroll
    for (int rf = 0; rf < 8; ++rf) acc[ef][rf] = z4;
  gemm_kloop<8>(wb2, smem, abase0, asw, koff0, acc);
  __syncthreads();   // all waves done reading H

  float pn[8] = {0.f, 0.f, 0.f, 0.f, 0.f, 0.f, 0.f, 0.f};
#pragma unroll
  for (int ef = 0; ef < 4; ++ef) {
    const int eb = (wv * 64 + ef * 16 + lhi * 4) * 2;
#pragma unroll
    for (int rf = 0; rf < 8; ++rf) {
      float a0 = acc[ef][rf][0] + b2v[ef].x;
      float a1 = acc[ef][rf][1] + b2v[ef].y;
      float a2 = acc[ef][rf][2] + b2v[ef].z;
      float a3 = acc[ef][rf][3] + b2v[ef].w;
      pn[rf] += a0 * a0 + a1 * a1 + a2 * a2 + a3 * a3;
      *(uint2*)(smem + rf * 8192 + abase0 + (eb ^ asw)) =
          make_uint2(cvtpk(a0, a1), cvtpk(a2, a3));
    }
  }
  // reduce norm partials over the 4 lanes sharing l15 (lhi = 0..3)
#pragma unroll
  for (int rf = 0; rf < 8; ++rf) {
    pn[rf] += __shfl_xor(pn[rf], 16);
    pn[rf] += __shfl_xor(pn[rf], 32);
  }
  __syncthreads();   // P staged

  // ========= qr GEMM (M-split): qr[k][m] = sum_d Pq[k][d]*Pr[m][d] =========
  f32x4 accC[4];
#pragma unroll
  for (int n = 0; n < 4; ++n) accC[n] = z4;
#pragma unroll
  for (int ks = 0; ks < 8; ++ks) {
    const int ko = (ks * 64 + koff0) ^ asw;
    s16x8 aQ = *(const s16x8*)(smem + wv * 8192 + abase0 + ko);
#pragma unroll
    for (int n = 0; n < 4; ++n) {
      s16x8 bR = *(const s16x8*)(smem + 32768 + n * 8192 + abase0 + ko);
      accC[n] = MFMA16(aQ, bR, accC[n]);
    }
  }
  __syncthreads();   // P reads done -> tile region free for norm exchange

  // nbuf[wv*128 + row] = this wave's 64-col partial for row
  if (lhi == 0) {
#pragma unroll
    for (int rf = 0; rf < 8; ++rf) nbuf[wv * 128 + rf * 16 + l15] = pn[rf];
  }
  __syncthreads();

  f32x4 nq = z4;
#pragma unroll
  for (int w = 0; w < 4; ++w)
    nq += *(const f32x4*)(nbuf + w * 128 + wv * 16 + lhi * 4);
  float nR[4];
#pragma unroll
  for (int n = 0; n < 4; ++n) {
    float s = 0.0f;
#pragma unroll
    for (int w = 0; w < 4; ++w) s += nbuf[w * 128 + 64 + n * 16 + l15];
    nR[n] = s;
  }

  // C = sqrt(max(q2 + r2 - 2*qr, 0)) -> direct global store
  float* Cb = out + OFF_C + (size_t)b * 4096;
#pragma unroll
  for (int n = 0; n < 4; ++n)
#pragma unroll
    for (int j = 0; j < 4; ++j) {
      float d2 = nq[j] + nR[n] - 2.0f * accC[n][j];
      Cb[(wv * 16 + lhi * 4 + j) * 64 + n * 16 + l15] = sqrtf(fmaxf(d2, 0.0f));
    }
}

// ======================= Kernel B: Sinkhorn + MESH + outputs =======================
__global__ void __launch_bounds__(256, 4)
sinkhorn_solve(const float* __restrict__ mask_r, float* __restrict__ out) {
  __shared__ float tile[64 * 65];   // C load staging, then T tile for MESH
  __shared__ float u_arr[64], w_arr[64], red[4];

  const int b    = blockIdx.x;
  const int tid  = threadIdx.x;
  const int wv   = tid >> 6;
  const int lane = tid & 63;
  const int rk   = tid >> 2;    // row (or col) this thread group owns
  const int g    = tid & 3;     // 4-lane split of the 64-wide reduction
  const int e0   = g * 16;

  const float* Cb = out + OFF_C + (size_t)b * 4096;

  // load C coalesced -> LDS tile
#pragma unroll
  for (int i = 0; i < 16; ++i) {
    int idx = tid + 256 * i;
    tile[(idx >> 6) * 65 + (idx & 63)] = Cb[idx];
  }
  if (tid < 64) w_arr[tid] = __logf(fmaxf(mask_r[(size_t)b * 64 + tid], 1e-8f));
  __syncthreads();

  // C slices into registers: cn = row slice * (-1/eps), cc = col slice * (-1/eps)
  float cn[16], cc[16];
#pragma unroll
  for (int i = 0; i < 16; ++i) {
    cn[i] = tile[rk * 65 + e0 + i] * -20.0f;
    cc[i] = tile[(e0 + i) * 65 + rk] * -20.0f;
  }

  // ---------------- Sinkhorn: u = -lse_m(cn + w); w = -lse_k(cc + u) ----------------
  for (int it = 0; it < 20; ++it) {
    {
      float v[16];
#pragma unroll
      for (int i = 0; i < 16; ++i) v[i] = cn[i] + w_arr[e0 + i];
      float mx = v[0];
#pragma unroll
      for (int i = 1; i < 16; ++i) mx = fmaxf(mx, v[i]);
      float s = 0.0f;
#pragma unroll
      for (int i = 0; i < 16; ++i) s += __expf(v[i] - mx);
#pragma unroll
      for (int d = 1; d < 4; d <<= 1) {
        float mo = __shfl_xor(mx, d), so = __shfl_xor(s, d);
        float nm = fmaxf(mx, mo);
        s = s * __expf(mx - nm) + so * __expf(mo - nm);
        mx = nm;
      }
      if (g == 0) u_arr[rk] = -(mx + __logf(s));
    }
    __syncthreads();
    {
      float v[16];
#pragma unroll
      for (int i = 0; i < 16; ++i) v[i] = cc[i] + u_arr[e0 + i];
      float mx = v[0];
#pragma unroll
      for (int i = 1; i < 16; ++i) mx = fmaxf(mx, v[i]);
      float s = 0.0f;
#pragma unroll
      for (int i = 0; i < 16; ++i) s += __expf(v[i] - mx);
#pragma unroll
      for (int d = 1; d < 4; d <<= 1) {
        float mo = __shfl_xor(mx, d), so = __shfl_xor(s, d);
        float nm = fmaxf(mx, mo);
        s = s * __expf(mx - nm) + so * __expf(mo - nm);
        mx = nm;
      }
      if (g == 0) w_arr[rk] = -(mx + __logf(s));
    }
    __syncthreads();
  }

  // ---------------- T = exp(cn + u + w), then MESH x3 ----------------
  float t[16];
  {
    float uk = u_arr[rk];
#pragma unroll
    for (int i = 0; i < 16; ++i) t[i] = __expf(cn[i] + uk + w_arr[e0 + i]);
  }
  for (int it = 0; it < 3; ++it) {
    if (it > 0) {
      __syncthreads();
#pragma unroll
      for (int i = 0; i < 16; ++i) t[i] = tile[rk * 65 + e0 + i];
    }
    // row: square + normalize by rowsum
    float s = 0.0f;
#pragma unroll
    for (int i = 0; i < 16; ++i) { t[i] *= t[i]; s += t[i]; }
    s += __shfl_xor(s, 1); s += __shfl_xor(s, 2);
    float inv = 1.0f / (s + 1e-8f);
#pragma unroll
    for (int i = 0; i < 16; ++i) tile[rk * 65 + e0 + i] = t[i] * inv;
    __syncthreads();
    // col: normalize by colsum
    float tc[16]; float cs = 0.0f;
#pragma unroll
    for (int i = 0; i < 16; ++i) { tc[i] = tile[(e0 + i) * 65 + rk]; cs += tc[i]; }
    cs += __shfl_xor(cs, 1); cs += __shfl_xor(cs, 2);
    inv = 1.0f / (cs + 1e-8f);
#pragma unroll
    for (int i = 0; i < 16; ++i) tile[(e0 + i) * 65 + rk] = tc[i] * inv;
  }
  __syncthreads();

  // ---------------- transport cost + similarity + T store ----------------
  {
    float part = 0.0f;
#pragma unroll
    for (int i = 0; i < 16; ++i)
      part += tile[rk * 65 + e0 + i] * (cn[i] * -0.05f);
#pragma unroll
    for (int d = 1; d < 64; d <<= 1) part += __shfl_xor(part, d);
    if (lane == 0) red[wv] = part;
  }
  __syncthreads();
  if (tid == 0) {
    float tc = red[0] + red[1] + red[2] + red[3];
    out[OFF_TC + b] = tc;
    out[b] = 1.0f / (1.0f + __expf(tc));
  }
  {
    float* Tout = out + OFF_T + (size_t)b * 4096;
#pragma unroll
    for (int i = 0; i < 16; ++i) {
      int idx = tid + 256 * i;
      Tout[idx] = tile[(idx >> 6) * 65 + (idx & 63)];
    }
  }
}

extern "C" void kernel_launch(void* const* d_in, const int* in_sizes, int n_in,
                              void* d_out, int out_size, void* d_ws, size_t ws_size,
                              hipStream_t stream) {
  const float* slots_q = (const float*)d_in[0];
  const float* slots_r = (const float*)d_in[1];
  // d_in[2] = mask_q: cancels out of T/T_hard/C/cost (row-rescaling invariance).
  const float* mask_r = (const float*)d_in[3];
  const float* W1 = (const float*)d_in[4];
  const float* b1 = (const float*)d_in[5];
  const float* W2 = (const float*)d_in[6];
  const float* b2 = (const float*)d_in[7];

  short* W1p = (short*)d_ws;            // fragment-major packed bf16 weights
  short* W2p = W1p + 65536;

  prep_w_kernel<<<256, 256, 0, stream>>>(W1, W2, W1p, W2p);
  proj_cost_kernel<<<2048, 256, 0, stream>>>(slots_q, slots_r, W1p, W2p, b1, b2,
                                             (float*)d_out);
  sinkhorn_solve<<<2048, 256, 0, stream>>>(mask_r, (float*)d_out);
}